// Round 3
// baseline (221.431 us; speedup 1.0000x reference)
//
#include <hip/hip_runtime.h>
#include <math.h>
#include <stdint.h>

// B=8, S=2048, D=512 single-head self-attention, fp32 in/out, fp16 MFMA inside.
// Round 10: faithful m201-style schedule (the proven 1563-TF structure):
//   per phase: [issue ds_reads for THIS phase] [stage prefetch chunks whose
//   region was fully read LAST phase] barrier; lgkmcnt(0); setprio(1);
//   16-MFMA cluster; setprio(0); barrier.  Counted vmcnt once per K-tile,
//   never drained in the main loop (loads span barriers). Barrier-skew gives
//   cross-wave MFMA/LDS overlap (r2 lesson: my 4-phase read->use-in-same-wave
//   schedule had none; MfmaUtil stuck at 23%).
//   - scores/proj: core256 = 256x256 tile, BK=64, 8 waves 2x4 (per-wave
//     128x64, acc[8][4]), LDS 128KB dbuf, 4 phases/tile, vmcnt(8) at P3.
//   - av: core128 = 256x128 (N=512 forces BN=128), waves 4x2 (per-wave
//     64x64), LDS 96KB, 2 phases/tile, vmcnt(5), B1 chunk staged one phase
//     early into the other buffer (its region is read in P1, so it can only
//     be overwritten at the NEXT tile's P0).
// Round-9 lesson: phase-split alone is not enough; the read->barrier->MFMA
// ordering (reads never consumed in the phase that issues them without an
// intervening barrier) is what creates the overlap.
// Round-7: XCD-aware block mapping (batch=bid&7) kept everywhere.
//
//  1. prep:        Xh = fp16(x);  W*T = fp16(W^T) for q,k,v
//  2. proj_mfma:   z=0: Qh=(Xh.Wq+bq)/sqrt(512)  z=1: Kh=Xh.Wk+bk
//                  z=2: Vt[b][d][s] = (Xh.Wv + bv)^T  (transposed GEMM)
//  3. scores_mfma: P[b] = fp16(exp(Qh.Kh^T))  UNNORMALIZED (scores ~N(0,1))
//  4. av_mfma:     out[b] = (P.V) * mask[row] / l[row]; l = rowsum(P) via
//                  fdot2 on the A-frags (read once per tile in P0).

typedef _Float16 f16x8 __attribute__((ext_vector_type(8)));
typedef _Float16 f16x4 __attribute__((ext_vector_type(4)));
typedef _Float16 f16x2 __attribute__((ext_vector_type(2)));
typedef float f32x4 __attribute__((ext_vector_type(4)));

__device__ __forceinline__ void async16(const _Float16* g, _Float16* l) {
    __builtin_amdgcn_global_load_lds(
        (const __attribute__((address_space(1))) unsigned int*)(uintptr_t)g,
        (__attribute__((address_space(3))) unsigned int*)(unsigned int)(uintptr_t)l,
        16, 0, 0);
}

__device__ __forceinline__ float frag_sum8(f16x8 v, float acc) {
#if __has_builtin(__builtin_amdgcn_fdot2)
    const f16x2 one2 = {(_Float16)1.f, (_Float16)1.f};
    const f16x2* p = (const f16x2*)&v;
    acc = __builtin_amdgcn_fdot2(p[0], one2, acc, false);
    acc = __builtin_amdgcn_fdot2(p[1], one2, acc, false);
    acc = __builtin_amdgcn_fdot2(p[2], one2, acc, false);
    acc = __builtin_amdgcn_fdot2(p[3], one2, acc, false);
#else
#pragma unroll
    for (int j = 0; j < 8; j++) acc += (float)v[j];
#endif
    return acc;
}

#define MFMA16(a, b, c) __builtin_amdgcn_mfma_f32_16x16x32_f16(a, b, c, 0, 0, 0)
#define BAR() __builtin_amdgcn_s_barrier()
#define LGKM0() asm volatile("s_waitcnt lgkmcnt(0)" ::: "memory")

// ---------------------------------------------------------------------------
// core256: acc[8][4] += A[row0:+256][0:K] . B[col0:+256][0:K]^T, BK=64.
// 8 waves 2(wm)x4(wn), per-wave 128x64. LDS chunk = 8 rows x 64 halves (1KB),
// staged by one async16 (pre-swizzled global source, linear LDS dest).
// Element A[row][k] lives at As[row*64 + ((k/8)^(row&7))*8 + k%8].
// Per-tile phases (quadrants of per-wave C):
//  P0: read A0(8)+B0(4)                 | Q(0..3, 0..1)
//  P1: read B1(4), stage A0own+B0own(4) | Q(0..3, 2..3)
//  P2: read A1(8), stage B1own(2)       | Q(4..7, 2..3)
//  P3: stage A1own(2), vmcnt(8)         | Q(4..7, 0..1)  (A1,B0 in regs)
// ---------------------------------------------------------------------------
template <int NT>
__device__ __forceinline__ void core256(
    const _Float16* __restrict__ A, const _Float16* __restrict__ B,
    int ld, int row0, int col0, _Float16* sm, f32x4 acc[8][4])
{
    const int tid = threadIdx.x, lane = tid & 63, wave = tid >> 6;
    const int wm = wave >> 2, wn = wave & 3;
    const int rc = lane >> 3;
    const int swz = ((lane & 7) ^ rc) * 8;
    const int fr = lane & 15, q = lane >> 4, fx = fr & 7;
    const size_t laneoff = (size_t)rc * ld + swz;

    // staging chunk sets: [0,1]=A0own [2,3]=B0own [4,5]=B1own [6,7]=A1own
    const _Float16* gc[8];
    int lc[8];
    {
        const int i0 = wave * 2, i1 = i0 + 1;
        const int a0 = (i0 < 8) ? i0 : i0 + 8;       // A0 chunks {0-7,16-23}
        const int a1 = (i1 < 8) ? i1 : i1 + 8;
        const int b0 = (i0 & 3) + (i0 >> 2) * 8;     // B0 chunks {0-3,8-11,16-19,24-27}
        const int b1 = (i1 & 3) + (i1 >> 2) * 8;
        gc[0] = A + (size_t)(row0 + 8 * a0) * ld + laneoff;       lc[0] = a0 * 512;
        gc[1] = A + (size_t)(row0 + 8 * a1) * ld + laneoff;       lc[1] = a1 * 512;
        gc[2] = B + (size_t)(col0 + 8 * b0) * ld + laneoff;       lc[2] = 16384 + b0 * 512;
        gc[3] = B + (size_t)(col0 + 8 * b1) * ld + laneoff;       lc[3] = 16384 + b1 * 512;
        gc[4] = B + (size_t)(col0 + 8 * (b0 + 4)) * ld + laneoff; lc[4] = 16384 + (b0 + 4) * 512;
        gc[5] = B + (size_t)(col0 + 8 * (b1 + 4)) * ld + laneoff; lc[5] = 16384 + (b1 + 4) * 512;
        gc[6] = A + (size_t)(row0 + 8 * (a0 + 8)) * ld + laneoff; lc[6] = (a0 + 8) * 512;
        gc[7] = A + (size_t)(row0 + 8 * (a1 + 8)) * ld + laneoff; lc[7] = (a1 + 8) * 512;
    }

    // prologue: tile 0 -> buf0, tile 1 -> buf1; keep tile1's 8 in flight
#pragma unroll
    for (int i = 0; i < 8; i++) async16(gc[i], sm + lc[i]);
#pragma unroll
    for (int i = 0; i < 8; i++) async16(gc[i] + 64, sm + 32768 + lc[i]);
    asm volatile("s_waitcnt vmcnt(8)" ::: "memory");
    BAR();

#pragma unroll 2
    for (int t = 0; t < NT; ++t) {
        const _Float16* As = sm + (t & 1) * 32768;
        const _Float16* Bs = As + 16384;
        _Float16* stg = sm + (t & 1) * 32768;          // buffer for tile t+2
        const int k2 = (t + 2) * 64;
        const bool pf = (t + 2 < NT);
        f16x8 a0f[4][2], a1f[4][2], b0f[2][2], b1f[2][2];

        // ---- P0: read A0 + B0
#pragma unroll
        for (int m = 0; m < 4; m++)
#pragma unroll
            for (int s = 0; s < 2; s++) {
                int ra = wm * 128 + m * 16 + fr;
                a0f[m][s] = *(const f16x8*)&As[ra * 64 + (((s * 4 + q) ^ fx) * 8)];
            }
#pragma unroll
        for (int n = 0; n < 2; n++)
#pragma unroll
            for (int s = 0; s < 2; s++) {
                int rb = wn * 64 + n * 16 + fr;
                b0f[n][s] = *(const f16x8*)&Bs[rb * 64 + (((s * 4 + q) ^ fx) * 8)];
            }
        BAR(); LGKM0();
        __builtin_amdgcn_s_setprio(1);
#pragma unroll
        for (int s = 0; s < 2; s++)
#pragma unroll
            for (int m = 0; m < 4; m++)
#pragma unroll
                for (int n = 0; n < 2; n++)
                    acc[m][n] = MFMA16(a0f[m][s], b0f[n][s], acc[m][n]);
        __builtin_amdgcn_s_setprio(0);
        BAR();

        // ---- P1: read B1; stage A0own+B0own of t+2 (regions read-done @P0)
#pragma unroll
        for (int n = 0; n < 2; n++)
#pragma unroll
            for (int s = 0; s < 2; s++) {
                int rb = wn * 64 + (2 + n) * 16 + fr;
                b1f[n][s] = *(const f16x8*)&Bs[rb * 64 + (((s * 4 + q) ^ fx) * 8)];
            }
        if (pf) {
#pragma unroll
            for (int i = 0; i < 4; i++) async16(gc[i] + k2, stg + lc[i]);
        }
        BAR(); LGKM0();
        __builtin_amdgcn_s_setprio(1);
#pragma unroll
        for (int s = 0; s < 2; s++)
#pragma unroll
            for (int m = 0; m < 4; m++)
#pragma unroll
                for (int n = 0; n < 2; n++)
                    acc[m][2 + n] = MFMA16(a0f[m][s], b1f[n][s], acc[m][2 + n]);
        __builtin_amdgcn_s_setprio(0);
        BAR();

        // ---- P2: read A1; stage B1own of t+2 (region read-done @P1)
#pragma unroll
        for (int m = 0; m < 4; m++)
#pragma unroll
            for (int s = 0; s < 2; s++) {
                int ra = wm * 128 + (4 + m) * 16 + fr;
                a1f[m][s] = *(const f16x8*)&As[ra * 64 + (((s * 4 + q) ^ fx) * 8)];
            }
        if (pf) {
            async16(gc[4] + k2, stg + lc[4]);
            async16(gc[5] + k2, stg + lc[5]);
        }
        BAR(); LGKM0();
        __builtin_amdgcn_s_setprio(1);
#pragma unroll
        for (int s = 0; s < 2; s++)
#pragma unroll
            for (int m = 0; m < 4; m++)
#pragma unroll
                for (int n = 0; n < 2; n++)
                    acc[4 + m][2 + n] = MFMA16(a1f[m][s], b1f[n][s], acc[4 + m][2 + n]);
        __builtin_amdgcn_s_setprio(0);
        BAR();

        // ---- P3: stage A1own of t+2 (read-done @P2); counted vmcnt; Q(1,0)
        if (pf) {
            async16(gc[6] + k2, stg + lc[6]);
            async16(gc[7] + k2, stg + lc[7]);
            asm volatile("s_waitcnt vmcnt(8)" ::: "memory");   // t+1 landed
        } else {
            asm volatile("s_waitcnt vmcnt(0)" ::: "memory");   // tail drain
        }
        __builtin_amdgcn_s_setprio(1);
#pragma unroll
        for (int s = 0; s < 2; s++)
#pragma unroll
            for (int m = 0; m < 4; m++)
#pragma unroll
                for (int n = 0; n < 2; n++)
                    acc[4 + m][n] = MFMA16(a1f[m][s], b0f[n][s], acc[4 + m][n]);
        __builtin_amdgcn_s_setprio(0);
        BAR();
    }
}

// ---------------------------------------------------------------------------
// core128: acc[4][4] += A[row0:+256][0:K] . B[col0:+128][0:K]^T, BK=64.
// 8 waves 4(wm)x2(wn), per-wave 64x64. LDS 96KB dbuf (A 32KB + B 16KB each).
//  P0: read A(8)+B0(4); stage B1own of t+1 -> other buf | Q(n=0,1) + rowsum
//  P1: read B1(4); stage Aown(4)+B0own(1) of t+2; vmcnt(5) | Q(n=2,3)
// ---------------------------------------------------------------------------
template <int NT, bool WITH_RS>
__device__ __forceinline__ void core128(
    const _Float16* __restrict__ A, const _Float16* __restrict__ B,
    int ld, int row0, int col0, _Float16* sm, f32x4 acc[4][4], float rs[4])
{
    const int tid = threadIdx.x, lane = tid & 63, wave = tid >> 6;
    const int wm = wave >> 1, wn = wave & 1;
    const int rc = lane >> 3;
    const int swz = ((lane & 7) ^ rc) * 8;
    const int fr = lane & 15, q = lane >> 4, fx = fr & 7;
    const size_t laneoff = (size_t)rc * ld + swz;

    const _Float16* gA[4]; int lA[4];
#pragma unroll
    for (int i = 0; i < 4; i++) {
        int c = wave * 4 + i;                         // A chunks 0..31
        gA[i] = A + (size_t)(row0 + 8 * c) * ld + laneoff;
        lA[i] = c * 512;
    }
    const int cb0 = (wave & 3) + (wave >> 2) * 8;     // B0 chunks {0-3,8-11}
    const _Float16* gB0 = B + (size_t)(col0 + 8 * cb0) * ld + laneoff;
    const _Float16* gB1 = B + (size_t)(col0 + 8 * (cb0 + 4)) * ld + laneoff;
    const int lB0 = 16384 + cb0 * 512;
    const int lB1 = 16384 + (cb0 + 4) * 512;

    // prologue: tile0 full (6), tile1 all but B1 (5); tile1.B1 at t=0 P0.
#pragma unroll
    for (int i = 0; i < 4; i++) async16(gA[i], sm + lA[i]);
    async16(gB0, sm + lB0);
    async16(gB1, sm + lB1);
#pragma unroll
    for (int i = 0; i < 4; i++) async16(gA[i] + 64, sm + 24576 + lA[i]);
    async16(gB0 + 64, sm + 24576 + lB0);
    asm volatile("s_waitcnt vmcnt(5)" ::: "memory");
    BAR();

#pragma unroll 2
    for (int t = 0; t < NT; ++t) {
        const _Float16* As = sm + (t & 1) * 24576;
        const _Float16* Bs = As + 16384;
        _Float16* stg  = sm + (t & 1) * 24576;         // tile t+2
        _Float16* stgn = sm + ((t + 1) & 1) * 24576;   // tile t+1 (B1)
        const int k1 = (t + 1) * 64;
        const int k2 = (t + 2) * 64;
        f16x8 af[4][2], b0f[2][2], b1f[2][2];

        // ---- P0: read A + B0; stage t+1's B1 into the other buffer
#pragma unroll
        for (int m = 0; m < 4; m++)
#pragma unroll
            for (int s = 0; s < 2; s++) {
                int ra = wm * 64 + m * 16 + fr;
                af[m][s] = *(const f16x8*)&As[ra * 64 + (((s * 4 + q) ^ fx) * 8)];
            }
#pragma unroll
        for (int n = 0; n < 2; n++)
#pragma unroll
            for (int s = 0; s < 2; s++) {
                int rb = wn * 64 + n * 16 + fr;
                b0f[n][s] = *(const f16x8*)&Bs[rb * 64 + (((s * 4 + q) ^ fx) * 8)];
            }
        if (t + 1 < NT) async16(gB1 + k1, stgn + lB1);
        BAR(); LGKM0();
        if (WITH_RS) {
#pragma unroll
            for (int m = 0; m < 4; m++)
#pragma unroll
                for (int s = 0; s < 2; s++) rs[m] = frag_sum8(af[m][s], rs[m]);
        }
        __builtin_amdgcn_s_setprio(1);
#pragma unroll
        for (int s = 0; s < 2; s++)
#pragma unroll
            for (int m = 0; m < 4; m++)
#pragma unroll
                for (int n = 0; n < 2; n++)
                    acc[m][n] = MFMA16(af[m][s], b0f[n][s], acc[m][n]);
        __builtin_amdgcn_s_setprio(0);
        BAR();

        // ---- P1: read B1; stage t+2's A + B0; counted vmcnt
#pragma unroll
        for (int n = 0; n < 2; n++)
#pragma unroll
            for (int s = 0; s < 2; s++) {
                int rb = wn * 64 + (2 + n) * 16 + fr;
                b1f[n][s] = *(const f16x8*)&Bs[rb * 64 + (((s * 4 + q) ^ fx) * 8)];
            }
        if (t + 2 < NT) {
#pragma unroll
            for (int i = 0; i < 4; i++) async16(gA[i] + k2, stg + lA[i]);
            async16(gB0 + k2, stg + lB0);
            asm volatile("s_waitcnt vmcnt(5)" ::: "memory");   // t+1 landed
        } else {
            asm volatile("s_waitcnt vmcnt(0)" ::: "memory");
        }
        BAR(); LGKM0();
        __builtin_amdgcn_s_setprio(1);
#pragma unroll
        for (int s = 0; s < 2; s++)
#pragma unroll
            for (int m = 0; m < 4; m++)
#pragma unroll
                for (int n = 0; n < 2; n++)
                    acc[m][2 + n] = MFMA16(af[m][s], b1f[n][s], acc[m][2 + n]);
        __builtin_amdgcn_s_setprio(0);
        BAR();
    }
}

// ---------------- 1. prep: x->fp16 and W->fp16 W^T --------------------------
__global__ __launch_bounds__(256) void prep(
    const float* __restrict__ x,
    const float* __restrict__ Wq, const float* __restrict__ Wk,
    const float* __restrict__ Wv,
    _Float16* __restrict__ Xh,
    _Float16* __restrict__ WqT, _Float16* __restrict__ WkT,
    _Float16* __restrict__ WvT)
{
    const int bid = blockIdx.x;
    if (bid < 8192) {                       // convert x: 8.4M elems / 1024
        int i = (bid * 256 + threadIdx.x) * 4;
        float4 v = *(const float4*)(x + i);
        f16x4 h;
        h.x = (_Float16)v.x; h.y = (_Float16)v.y;
        h.z = (_Float16)v.z; h.w = (_Float16)v.w;
        *(f16x4*)&Xh[i] = h;
    } else {                                // transpose W: 3 x 1024 blocks
        int t = bid - 8192;
        int z = t >> 10;
        const float* W = (z == 0) ? Wq : (z == 1) ? Wk : Wv;
        _Float16* Wt   = (z == 0) ? WqT : (z == 1) ? WkT : WvT;
        int idx = (t & 1023) * 256 + threadIdx.x;
        int n = idx >> 9, k = idx & 511;
        Wt[idx] = (_Float16)W[k * 512 + n];
    }
}

// ---------------- 2. projections --------------------------------------------
// grid (x=64, y=2, z=3). z<2: row0=bx*256 (X rows), col0=by*256.
// z=2: row0=by*256 (d), col0=bx*256 (s_global).
__global__ __launch_bounds__(512, 2) void proj_mfma(
    const _Float16* __restrict__ Xh,
    const _Float16* __restrict__ WqT, const float* __restrict__ bq,
    const _Float16* __restrict__ WkT, const float* __restrict__ bk,
    const _Float16* __restrict__ WvT, const float* __restrict__ bv,
    _Float16* __restrict__ Qh, _Float16* __restrict__ Kh,
    _Float16* __restrict__ Vt)
{
    __shared__ __align__(16) _Float16 smem[2 * 32768];
    const int z = blockIdx.z;
    f32x4 acc[8][4];
#pragma unroll
    for (int i = 0; i < 8; i++)
#pragma unroll
        for (int j = 0; j < 4; j++) acc[i][j] = (f32x4){0.f, 0.f, 0.f, 0.f};

    const int lane = threadIdx.x & 63, wave = threadIdx.x >> 6;
    const int wm = wave >> 2, wn = wave & 3;
    const int er = (lane >> 4) * 4, ec = lane & 15;

    if (z < 2) {
        const _Float16* Wt = (z == 0) ? WqT : WkT;
        const float* bias  = (z == 0) ? bq : bk;
        _Float16* P        = (z == 0) ? Qh : Kh;
        const float sc     = (z == 0) ? 0.04419417382415922f : 1.0f;
        const int row0 = blockIdx.x * 256, col0 = blockIdx.y * 256;
        core256<8>(Xh, Wt, 512, row0, col0, smem, acc);
#pragma unroll
        for (int mf = 0; mf < 8; mf++)
#pragma unroll
            for (int nf = 0; nf < 4; nf++) {
                int col = col0 + wn * 64 + nf * 16 + ec;
                float bb = bias[col];
#pragma unroll
                for (int r = 0; r < 4; r++) {
                    int row = row0 + wm * 128 + mf * 16 + er + r;
                    P[(size_t)row * 512 + col] = (_Float16)((acc[mf][nf][r] + bb) * sc);
                }
            }
    } else {
        // transposed V: out(row=d, col=s_global) = sum_k WvT[d][k] * Xh[s][k]
        const int row0 = blockIdx.y * 256;   // d (M=512)
        const int col0 = blockIdx.x * 256;   // s_global (N=16384)
        core256<8>(WvT, Xh, 512, row0, col0, smem, acc);
#pragma unroll
        for (int mf = 0; mf < 8; mf++)
#pragma unroll
            for (int nf = 0; nf < 4; nf++) {
                int col = col0 + wn * 64 + nf * 16 + ec;   // s_global
                size_t obase = (size_t)(col >> 11) * (512 * 2048) + (col & 2047);
#pragma unroll
                for (int r = 0; r < 4; r++) {
                    int row = row0 + wm * 128 + mf * 16 + er + r;  // d
                    Vt[obase + (size_t)row * 2048] = (_Float16)(acc[mf][nf][r] + bv[row]);
                }
            }
    }
}

// ---------------- 3. scores: P = exp(Q.K^T) (unnormalized) ------------------
// grid 512: batch = bid&7 (XCD pin: Q[b]+K[b]=4MB=one XCD L2), col fast.
__global__ __launch_bounds__(512, 2) void scores_mfma(
    const _Float16* __restrict__ Qh, const _Float16* __restrict__ Kh,
    _Float16* __restrict__ Sh)
{
    __shared__ __align__(16) _Float16 smem[2 * 32768];
    const int bid = blockIdx.x;
    const int b   = bid & 7;
    const int rem = bid >> 3;
    const int col0 = (rem & 7) * 256;
    const int row0 = (rem >> 3) * 256;

    const _Float16* A = Qh + (size_t)b * 2048 * 512;
    const _Float16* B = Kh + (size_t)b * 2048 * 512;
    _Float16* S = Sh + (size_t)b * 2048 * 2048;

    f32x4 acc[8][4];
#pragma unroll
    for (int i = 0; i < 8; i++)
#pragma unroll
        for (int j = 0; j < 4; j++) acc[i][j] = (f32x4){0.f, 0.f, 0.f, 0.f};

    core256<8>(A, B, 512, row0, col0, smem, acc);

    const int lane = threadIdx.x & 63, wave = threadIdx.x >> 6;
    const int wm = wave >> 2, wn = wave & 3;
    const int er = (lane >> 4) * 4, ec = lane & 15;
#pragma unroll
    for (int mf = 0; mf < 8; mf++)
#pragma unroll
        for (int nf = 0; nf < 4; nf++) {
            int col = col0 + wn * 64 + nf * 16 + ec;
#pragma unroll
            for (int r = 0; r < 4; r++) {
                int row = row0 + wm * 128 + mf * 16 + er + r;
                S[(size_t)row * 2048 + col] = (_Float16)__expf(acc[mf][nf][r]);
            }
        }
}

// ---------------- 4. out = (P.V) * mask / rowsum(P) -------------------------
// grid 256: batch = bid&7 (XCD pin: P[b] streams through one XCD L2,
// V[b]=2MB resident), col fastest.
__global__ __launch_bounds__(512, 2) void av_mfma(
    const _Float16* __restrict__ Sh, const _Float16* __restrict__ Vt,
    const float* __restrict__ mask, float* __restrict__ out)
{
    __shared__ __align__(16) _Float16 smem[2 * 24576];
    const int bid = blockIdx.x;
    const int b   = bid & 7;
    const int rem = bid >> 3;
    const int col0 = (rem & 3) * 128;
    const int row0 = (rem >> 2) * 256;

    const _Float16* A = Sh + (size_t)b * 2048 * 2048;
    const _Float16* B = Vt + (size_t)b * 512 * 2048;
    float* O = out + (size_t)b * 2048 * 512;
    const float* mk = mask + (size_t)b * 2048;

    f32x4 acc[4][4];
#pragma unroll
    for (int i = 0; i < 4; i++)
#pragma unroll
        for (int j = 0; j < 4; j++) acc[i][j] = (f32x4){0.f, 0.f, 0.f, 0.f};
    float rs[4] = {0.f, 0.f, 0.f, 0.f};

    core128<32, true>(A, B, 2048, row0, col0, smem, acc, rs);

    const int lane = threadIdx.x & 63, wave = threadIdx.x >> 6;
    const int wm = wave >> 1, wn = wave & 1;
    const int er = (lane >> 4) * 4, ec = lane & 15;

    // rs[mf]: partial rowsum of row (wm*64+mf*16+(lane&15)) over this lane's
    // k-chunks; butterfly over the 4 q-groups -> full rowsum.
#pragma unroll
    for (int mf = 0; mf < 4; mf++) {
        rs[mf] += __shfl_xor(rs[mf], 16, 64);
        rs[mf] += __shfl_xor(rs[mf], 32, 64);
    }
    __syncthreads();                       // all waves out of the GEMM loop
    float* l_s = (float*)smem;             // alias dead staging LDS
    if (wn == 0 && lane < 16) {
#pragma unroll
        for (int mf = 0; mf < 4; mf++) l_s[wm * 64 + mf * 16 + lane] = rs[mf];
    }
    __syncthreads();

#pragma unroll
    for (int mf = 0; mf < 4; mf++)
#pragma unroll
        for (int r = 0; r < 4; r++) {
            int lrow = wm * 64 + mf * 16 + er + r;
            int row = row0 + lrow;
            float s = mk[row] / l_s[lrow];
#pragma unroll
            for (int nf = 0; nf < 4; nf++) {
                int col = col0 + wn * 64 + nf * 16 + ec;
                O[(size_t)row * 512 + col] = acc[mf][nf][r] * s;
            }
        }
}

extern "C" void kernel_launch(void* const* d_in, const int* in_sizes, int n_in,
                              void* d_out, int out_size, void* d_ws, size_t ws_size,
                              hipStream_t stream) {
    const float* x    = (const float*)d_in[0];
    const float* mask = (const float*)d_in[1];
    const float* Wq   = (const float*)d_in[2];
    const float* bq   = (const float*)d_in[3];
    const float* Wk   = (const float*)d_in[4];
    const float* bk   = (const float*)d_in[5];
    const float* Wv   = (const float*)d_in[6];
    const float* bv   = (const float*)d_in[7];
    float* out = (float*)d_out;

    const size_t BSD = (size_t)8 * 2048 * 512;       // 8.4M halves
    _Float16* base = (_Float16*)d_ws;
    _Float16* Qh  = base;
    _Float16* Kh  = Qh + BSD;
    _Float16* Vt  = Kh + BSD;                         // [b][d][s]
    _Float16* WqT = Vt + BSD;
    _Float16* WkT = WqT + 512 * 512;
    _Float16* WvT = WkT + 512 * 512;
    _Float16* Xh  = WvT + 512 * 512;
    _Float16* Sh  = Xh;                               // Xh dead after proj

    prep<<<dim3(8192 + 3 * 1024), dim3(256), 0, stream>>>(
        x, Wq, Wk, Wv, Xh, WqT, WkT, WvT);
    proj_mfma<<<dim3(64, 2, 3), dim3(512), 0, stream>>>(
        Xh, WqT, bq, WkT, bk, WvT, bv, Qh, Kh, Vt);
    scores_mfma<<<dim3(512), dim3(512), 0, stream>>>(Qh, Kh, Sh);
    av_mfma<<<dim3(256), dim3(512), 0, stream>>>(Sh, Vt, mask, out);
}

// Round 4
// 210.922 us; speedup vs baseline: 1.0498x; 1.0498x over previous
//
#include <hip/hip_runtime.h>
#include <math.h>
#include <stdint.h>

// B=8, S=2048, D=512 single-head self-attention, fp32 in/out, fp16 MFMA inside.
// Round 11: keep the m201-style phase schedule (r3) but at HALF the tile so
// TWO blocks fit per CU (the one factor never yet combined with phases):
//   - core: 128x128 tile, 4 waves 2x2 (per-wave 64x64), BK=64, dbuf LDS 64KB
//     (exactly 2 blocks/CU; 160KB-64KB*2 = 32KB slack), VGPR ~150 -> 8 waves/CU.
//   - per tile 2 phases, each: [ds_reads for this phase][stage into regions
//     read-complete last phase] BAR; lgkmcnt(0); setprio(1); 16 MFMA;
//     setprio(0); BAR.  vmcnt(6) once per tile, drained only in the tail.
//   - rationale (r0-r3 post-mortem): all 1-block/CU phase kernels pin at
//     MfmaUtil ~25% with VALU/HBM/conflicts low = stall-bound; m97/m114 show
//     co-resident blocks are what fill barrier+waitcnt stalls; m97's 912 TF
//     had ~3 blocks/CU. 2 blocks/CU x phase schedule = both mechanisms.
//   - grids 4x finer: av 512, scores 2048, proj 1536 blocks -> XCD-pin
//     imbalance and tails amortize.
// Round-7: XCD-aware mapping (batch=bid&7) kept.
//
//  1. prep:        Xh = fp16(x);  W*T = fp16(W^T) for q,k,v
//  2. proj_mfma:   z=0: Qh=(Xh.Wq+bq)/sqrt(512)  z=1: Kh=Xh.Wk+bk
//                  z=2: Vt[b][d][s] = (Xh.Wv + bv)^T  (transposed GEMM)
//  3. scores_mfma: P[b] = fp16(exp(Qh.Kh^T))  UNNORMALIZED (scores ~N(0,1))
//  4. av_mfma:     out[b] = (P.V) * mask[row] / l[row]; l = rowsum(P) via
//                  fdot2 on the A-frags (P0 covers all k of the tile).

typedef _Float16 f16x8 __attribute__((ext_vector_type(8)));
typedef _Float16 f16x4 __attribute__((ext_vector_type(4)));
typedef _Float16 f16x2 __attribute__((ext_vector_type(2)));
typedef float f32x4 __attribute__((ext_vector_type(4)));

__device__ __forceinline__ void async16(const _Float16* g, _Float16* l) {
    __builtin_amdgcn_global_load_lds(
        (const __attribute__((address_space(1))) unsigned int*)(uintptr_t)g,
        (__attribute__((address_space(3))) unsigned int*)(unsigned int)(uintptr_t)l,
        16, 0, 0);
}

__device__ __forceinline__ float frag_sum8(f16x8 v, float acc) {
#if __has_builtin(__builtin_amdgcn_fdot2)
    const f16x2 one2 = {(_Float16)1.f, (_Float16)1.f};
    const f16x2* p = (const f16x2*)&v;
    acc = __builtin_amdgcn_fdot2(p[0], one2, acc, false);
    acc = __builtin_amdgcn_fdot2(p[1], one2, acc, false);
    acc = __builtin_amdgcn_fdot2(p[2], one2, acc, false);
    acc = __builtin_amdgcn_fdot2(p[3], one2, acc, false);
#else
#pragma unroll
    for (int j = 0; j < 8; j++) acc += (float)v[j];
#endif
    return acc;
}

#define MFMA16(a, b, c) __builtin_amdgcn_mfma_f32_16x16x32_f16(a, b, c, 0, 0, 0)
#define BAR() __builtin_amdgcn_s_barrier()
#define LGKM0() asm volatile("s_waitcnt lgkmcnt(0)" ::: "memory")

// ---------------------------------------------------------------------------
// core: acc[4][4] += A[row0:+128][0:K] . B[col0:+128][0:K]^T, BK=64, 4 waves.
// LDS buffer = 32KB: A chunks 0..15 at [0,8192), B chunks 0..15 at [8192,16384),
// chunk = 8 rows x 64 halves (1KB), one async16 (pre-swizzled global source,
// linear LDS dest). Element [row][k] at buf[row*64 + ((k/8)^(row&7))*8 + k%8].
// Read regions: P0 = A(all) + B-early (chunks {0-3,8-11}); P1 = B-late
// ({4-7,12-15}).  Stage discipline: only into regions read-complete at the
// previous phase boundary.  Per-wave staging: 4 A + 2 B-early + 2 B-late.
//  P0: read A(8)+Bearly(4); stage t+1's B-late -> other buf  | MFMA n=0,1
//  P1: read Blate(4); stage t+2's A+Bearly -> this buf; vmcnt(6) | MFMA n=2,3
// ---------------------------------------------------------------------------
template <int NT, bool WITH_RS>
__device__ __forceinline__ void core128sq(
    const _Float16* __restrict__ A, const _Float16* __restrict__ B,
    int ld, int row0, int col0, _Float16* sm, f32x4 acc[4][4], float rs[4])
{
    const int tid = threadIdx.x, lane = tid & 63, wave = tid >> 6;
    const int wm = wave >> 1, wn = wave & 1;
    const int rc = lane >> 3;
    const int swz = ((lane & 7) ^ rc) * 8;
    const int fr = lane & 15, q = lane >> 4, fx = fr & 7;
    const size_t laneoff = (size_t)rc * ld + swz;

    const _Float16* gA[4]; int lA[4];
#pragma unroll
    for (int i = 0; i < 4; i++) {
        int c = wave * 4 + i;                        // A chunks 0..15
        gA[i] = A + (size_t)(row0 + 8 * c) * ld + laneoff;
        lA[i] = c * 512;
    }
    const _Float16* gBe[2]; const _Float16* gBl[2]; int lBe[2], lBl[2];
#pragma unroll
    for (int i = 0; i < 2; i++) {
        int idx = wave * 2 + i;                      // 0..7
        int je = (idx & 3) + (idx >> 2) * 8;         // early {0-3,8-11}
        int jl = je + 4;                             // late  {4-7,12-15}
        gBe[i] = B + (size_t)(col0 + 8 * je) * ld + laneoff;
        gBl[i] = B + (size_t)(col0 + 8 * jl) * ld + laneoff;
        lBe[i] = 8192 + je * 512;
        lBl[i] = 8192 + jl * 512;
    }

    // prologue: tile0 full (8/wave), tile1 A+Bearly (6/wave); vmcnt(6)=t0 done
#pragma unroll
    for (int i = 0; i < 4; i++) async16(gA[i], sm + lA[i]);
#pragma unroll
    for (int i = 0; i < 2; i++) async16(gBe[i], sm + lBe[i]);
#pragma unroll
    for (int i = 0; i < 2; i++) async16(gBl[i], sm + lBl[i]);
#pragma unroll
    for (int i = 0; i < 4; i++) async16(gA[i] + 64, sm + 16384 + lA[i]);
#pragma unroll
    for (int i = 0; i < 2; i++) async16(gBe[i] + 64, sm + 16384 + lBe[i]);
    asm volatile("s_waitcnt vmcnt(6)" ::: "memory");
    BAR();

#pragma unroll 2
    for (int t = 0; t < NT; ++t) {
        const _Float16* As = sm + (t & 1) * 16384;
        const _Float16* Bs = As + 8192;
        f16x8 af[4][2], b0f[2][2], b1f[2][2];

        // ---- P0: read A + B-early; stage t+1's B-late into the other buffer
#pragma unroll
        for (int m = 0; m < 4; m++)
#pragma unroll
            for (int s = 0; s < 2; s++) {
                int ra = wm * 64 + m * 16 + fr;
                af[m][s] = *(const f16x8*)&As[ra * 64 + (((s * 4 + q) ^ fx) * 8)];
            }
#pragma unroll
        for (int n = 0; n < 2; n++)
#pragma unroll
            for (int s = 0; s < 2; s++) {
                int rb = wn * 64 + n * 16 + fr;
                b0f[n][s] = *(const f16x8*)&Bs[rb * 64 + (((s * 4 + q) ^ fx) * 8)];
            }
        if (t + 1 < NT) {
            _Float16* nb = sm + ((t + 1) & 1) * 16384;
#pragma unroll
            for (int i = 0; i < 2; i++)
                async16(gBl[i] + (t + 1) * 64, nb + lBl[i]);
        }
        BAR(); LGKM0();
        if (WITH_RS) {
#pragma unroll
            for (int m = 0; m < 4; m++)
#pragma unroll
                for (int s = 0; s < 2; s++) rs[m] = frag_sum8(af[m][s], rs[m]);
        }
        __builtin_amdgcn_s_setprio(1);
#pragma unroll
        for (int s = 0; s < 2; s++)
#pragma unroll
            for (int m = 0; m < 4; m++)
#pragma unroll
                for (int n = 0; n < 2; n++)
                    acc[m][n] = MFMA16(af[m][s], b0f[n][s], acc[m][n]);
        __builtin_amdgcn_s_setprio(0);
        BAR();

        // ---- P1: read B-late; stage t+2's A+B-early into this buffer
#pragma unroll
        for (int n = 0; n < 2; n++)
#pragma unroll
            for (int s = 0; s < 2; s++) {
                int rb = wn * 64 + (2 + n) * 16 + fr;
                b1f[n][s] = *(const f16x8*)&Bs[rb * 64 + (((s * 4 + q) ^ fx) * 8)];
            }
        if (t + 2 < NT) {
            _Float16* stg = sm + (t & 1) * 16384;
            const int k2 = (t + 2) * 64;
#pragma unroll
            for (int i = 0; i < 4; i++) async16(gA[i] + k2, stg + lA[i]);
#pragma unroll
            for (int i = 0; i < 2; i++) async16(gBe[i] + k2, stg + lBe[i]);
            asm volatile("s_waitcnt vmcnt(6)" ::: "memory");   // t+1 landed
        } else {
            asm volatile("s_waitcnt vmcnt(0)" ::: "memory");   // tail drain
        }
        BAR(); LGKM0();
        __builtin_amdgcn_s_setprio(1);
#pragma unroll
        for (int s = 0; s < 2; s++)
#pragma unroll
            for (int m = 0; m < 4; m++)
#pragma unroll
                for (int n = 0; n < 2; n++)
                    acc[m][2 + n] = MFMA16(af[m][s], b1f[n][s], acc[m][2 + n]);
        __builtin_amdgcn_s_setprio(0);
        BAR();
    }
}

// ---------------- 1. prep: x->fp16 and W->fp16 W^T --------------------------
__global__ __launch_bounds__(256) void prep(
    const float* __restrict__ x,
    const float* __restrict__ Wq, const float* __restrict__ Wk,
    const float* __restrict__ Wv,
    _Float16* __restrict__ Xh,
    _Float16* __restrict__ WqT, _Float16* __restrict__ WkT,
    _Float16* __restrict__ WvT)
{
    const int bid = blockIdx.x;
    if (bid < 8192) {                       // convert x: 8.4M elems / 1024
        int i = (bid * 256 + threadIdx.x) * 4;
        float4 v = *(const float4*)(x + i);
        f16x4 h;
        h.x = (_Float16)v.x; h.y = (_Float16)v.y;
        h.z = (_Float16)v.z; h.w = (_Float16)v.w;
        *(f16x4*)&Xh[i] = h;
    } else {                                // transpose W: 3 x 1024 blocks
        int t = bid - 8192;
        int z = t >> 10;
        const float* W = (z == 0) ? Wq : (z == 1) ? Wk : Wv;
        _Float16* Wt   = (z == 0) ? WqT : (z == 1) ? WkT : WvT;
        int idx = (t & 1023) * 256 + threadIdx.x;
        int n = idx >> 9, k = idx & 511;
        Wt[idx] = (_Float16)W[k * 512 + n];
    }
}

// ---------------- 2. projections --------------------------------------------
// grid (x=128, y=4, z=3), 256 thr. z<2: row0=bx*128 (X rows), col0=by*128.
// z=2: row0=by*128 (d), col0=bx*128 (s_global). 4 col-blocks of one row-tile
// have bids differing by 128 (=0 mod 8) -> same XCD -> X rows fetched once.
__global__ __launch_bounds__(256, 2) void proj_mfma(
    const _Float16* __restrict__ Xh,
    const _Float16* __restrict__ WqT, const float* __restrict__ bq,
    const _Float16* __restrict__ WkT, const float* __restrict__ bk,
    const _Float16* __restrict__ WvT, const float* __restrict__ bv,
    _Float16* __restrict__ Qh, _Float16* __restrict__ Kh,
    _Float16* __restrict__ Vt)
{
    __shared__ __align__(16) _Float16 smem[2 * 16384];
    const int z = blockIdx.z;
    f32x4 acc[4][4];
#pragma unroll
    for (int i = 0; i < 4; i++)
#pragma unroll
        for (int j = 0; j < 4; j++) acc[i][j] = (f32x4){0.f, 0.f, 0.f, 0.f};
    float rs_unused[4];

    const int lane = threadIdx.x & 63, wave = threadIdx.x >> 6;
    const int wm = wave >> 1, wn = wave & 1;
    const int er = (lane >> 4) * 4, ec = lane & 15;  // C/D: col=lane&15

    if (z < 2) {
        const _Float16* Wt = (z == 0) ? WqT : WkT;
        const float* bias  = (z == 0) ? bq : bk;
        _Float16* P        = (z == 0) ? Qh : Kh;
        const float sc     = (z == 0) ? 0.04419417382415922f : 1.0f;
        const int row0 = blockIdx.x * 128, col0 = blockIdx.y * 128;
        core128sq<8, false>(Xh, Wt, 512, row0, col0, smem, acc, rs_unused);
#pragma unroll
        for (int tm = 0; tm < 4; tm++)
#pragma unroll
            for (int tn = 0; tn < 4; tn++) {
                int col = col0 + wn * 64 + tn * 16 + ec;
                float bb = bias[col];
#pragma unroll
                for (int r = 0; r < 4; r++) {
                    int row = row0 + wm * 64 + tm * 16 + er + r;
                    P[(size_t)row * 512 + col] = (_Float16)((acc[tm][tn][r] + bb) * sc);
                }
            }
    } else {
        // transposed V: out(row=d, col=s_global) = sum_k WvT[d][k] * Xh[s][k]
        const int row0 = blockIdx.y * 128;   // d (M=512)
        const int col0 = blockIdx.x * 128;   // s_global (N=16384)
        core128sq<8, false>(WvT, Xh, 512, row0, col0, smem, acc, rs_unused);
#pragma unroll
        for (int tm = 0; tm < 4; tm++)
#pragma unroll
            for (int tn = 0; tn < 4; tn++) {
                int col = col0 + wn * 64 + tn * 16 + ec;   // s_global
                size_t obase = (size_t)(col >> 11) * (512 * 2048) + (col & 2047);
#pragma unroll
                for (int r = 0; r < 4; r++) {
                    int row = row0 + wm * 64 + tm * 16 + er + r;  // d
                    Vt[obase + (size_t)row * 2048] = (_Float16)(acc[tm][tn][r] + bv[row]);
                }
            }
    }
}

// ---------------- 3. scores: P = exp(Q.K^T) (unnormalized) ------------------
// grid 2048: batch = bid&7 (XCD pin: Q[b]+K[b]=4MB=one XCD L2), col fastest.
__global__ __launch_bounds__(256, 2) void scores_mfma(
    const _Float16* __restrict__ Qh, const _Float16* __restrict__ Kh,
    _Float16* __restrict__ Sh)
{
    __shared__ __align__(16) _Float16 smem[2 * 16384];
    const int bid = blockIdx.x;
    const int b   = bid & 7;
    const int rem = bid >> 3;
    const int col0 = (rem & 15) * 128;
    const int row0 = (rem >> 4) * 128;

    const _Float16* A = Qh + (size_t)b * 2048 * 512;
    const _Float16* B = Kh + (size_t)b * 2048 * 512;
    _Float16* S = Sh + (size_t)b * 2048 * 2048;

    f32x4 acc[4][4];
#pragma unroll
    for (int i = 0; i < 4; i++)
#pragma unroll
        for (int j = 0; j < 4; j++) acc[i][j] = (f32x4){0.f, 0.f, 0.f, 0.f};
    float rs_unused[4];

    core128sq<8, false>(A, B, 512, row0, col0, smem, acc, rs_unused);

    const int lane = threadIdx.x & 63, wave = threadIdx.x >> 6;
    const int wm = wave >> 1, wn = wave & 1;
    const int er = (lane >> 4) * 4, ec = lane & 15;
#pragma unroll
    for (int tm = 0; tm < 4; tm++)
#pragma unroll
        for (int tn = 0; tn < 4; tn++) {
            int col = col0 + wn * 64 + tn * 16 + ec;
#pragma unroll
            for (int r = 0; r < 4; r++) {
                int row = row0 + wm * 64 + tm * 16 + er + r;
                S[(size_t)row * 2048 + col] = (_Float16)__expf(acc[tm][tn][r]);
            }
        }
}

// ---------------- 4. out = (P.V) * mask / rowsum(P) -------------------------
// grid 512: batch = bid&7 (XCD pin: P[b] streams through one XCD L2,
// V[b]=2MB resident), col fastest -> the 4 col-blocks of one row-group run
// adjacently and share P rows.
__global__ __launch_bounds__(256, 2) void av_mfma(
    const _Float16* __restrict__ Sh, const _Float16* __restrict__ Vt,
    const float* __restrict__ mask, float* __restrict__ out)
{
    __shared__ __align__(16) _Float16 smem[2 * 16384];
    const int bid = blockIdx.x;
    const int b   = bid & 7;
    const int rem = bid >> 3;
    const int col0 = (rem & 3) * 128;
    const int row0 = (rem >> 2) * 128;

    const _Float16* A = Sh + (size_t)b * 2048 * 2048;
    const _Float16* B = Vt + (size_t)b * 512 * 2048;
    float* O = out + (size_t)b * 2048 * 512;
    const float* mk = mask + (size_t)b * 2048;

    f32x4 acc[4][4];
#pragma unroll
    for (int i = 0; i < 4; i++)
#pragma unroll
        for (int j = 0; j < 4; j++) acc[i][j] = (f32x4){0.f, 0.f, 0.f, 0.f};
    float rs[4] = {0.f, 0.f, 0.f, 0.f};

    core128sq<32, true>(A, B, 2048, row0, col0, smem, acc, rs);

    const int lane = threadIdx.x & 63, wave = threadIdx.x >> 6;
    const int wm = wave >> 1, wn = wave & 1;
    const int er = (lane >> 4) * 4, ec = lane & 15;

    // rs[tm]: partial rowsum of row (wm*64+tm*16+(lane&15)) over this lane's
    // k-chunks; butterfly over the 4 q-groups -> full rowsum.
#pragma unroll
    for (int tm = 0; tm < 4; tm++) {
        rs[tm] += __shfl_xor(rs[tm], 16, 64);
        rs[tm] += __shfl_xor(rs[tm], 32, 64);
    }
    __syncthreads();                       // all waves out of the GEMM loop
    float* l_s = (float*)smem;             // alias dead staging LDS
    if (wn == 0 && lane < 16) {
#pragma unroll
        for (int tm = 0; tm < 4; tm++) l_s[wm * 64 + tm * 16 + lane] = rs[tm];
    }
    __syncthreads();

#pragma unroll
    for (int tm = 0; tm < 4; tm++)
#pragma unroll
        for (int r = 0; r < 4; r++) {
            int lrow = wm * 64 + tm * 16 + er + r;
            int row = row0 + lrow;
            float s = mk[row] / l_s[lrow];
#pragma unroll
            for (int tn = 0; tn < 4; tn++) {
                int col = col0 + wn * 64 + tn * 16 + ec;
                O[(size_t)row * 512 + col] = acc[tm][tn][r] * s;
            }
        }
}

extern "C" void kernel_launch(void* const* d_in, const int* in_sizes, int n_in,
                              void* d_out, int out_size, void* d_ws, size_t ws_size,
                              hipStream_t stream) {
    const float* x    = (const float*)d_in[0];
    const float* mask = (const float*)d_in[1];
    const float* Wq   = (const float*)d_in[2];
    const float* bq   = (const float*)d_in[3];
    const float* Wk   = (const float*)d_in[4];
    const float* bk   = (const float*)d_in[5];
    const float* Wv   = (const float*)d_in[6];
    const float* bv   = (const float*)d_in[7];
    float* out = (float*)d_out;

    const size_t BSD = (size_t)8 * 2048 * 512;       // 8.4M halves
    _Float16* base = (_Float16*)d_ws;
    _Float16* Qh  = base;
    _Float16* Kh  = Qh + BSD;
    _Float16* Vt  = Kh + BSD;                         // [b][d][s]
    _Float16* WqT = Vt + BSD;
    _Float16* WkT = WqT + 512 * 512;
    _Float16* WvT = WkT + 512 * 512;
    _Float16* Xh  = WvT + 512 * 512;
    _Float16* Sh  = Xh;                               // Xh dead after proj

    prep<<<dim3(8192 + 3 * 1024), dim3(256), 0, stream>>>(
        x, Wq, Wk, Wv, Xh, WqT, WkT, WvT);
    proj_mfma<<<dim3(128, 4, 3), dim3(256), 0, stream>>>(
        Xh, WqT, bq, WkT, bk, WvT, bv, Qh, Kh, Vt);
    scores_mfma<<<dim3(2048), dim3(256), 0, stream>>>(Qh, Kh, Sh);
    av_mfma<<<dim3(512), dim3(256), 0, stream>>>(Sh, Vt, mask, out);
}